// Round 12
// baseline (87.686 us; speedup 1.0000x reference)
//
#include <hip/hip_runtime.h>

// Problem constants (from reference)
#define NPIX     786432                     // C*H*W = 3*512*512
#define NSP      55050                      // noise pixels per sample
#define BATCH    64
#define LOG_CHUNK 15
#define CHUNK_PX (1 << LOG_CHUNK)           // 32768 pixels per chunk
#define NCHUNK   (NPIX / CHUNK_PX)          // 24 chunks per sample
#define BINB     16                         // bin blocks per sample
#define CAP_B    224                        // entries per (sample,chunk,binblock)
#define F4_PER_CHUNK (CHUNK_PX / 4)         // 8192 float4
#define MASK_WORDS   (CHUNK_PX / 16)        // 2048 u32 = 8 KB LDS (2 bits/px)
#define PF       8                          // prefetched stream iterations

// ws layout: u32 counts[64][24][16] @ 0 (fully rewritten every call);
//            u16 entries[64][24][16][CAP_B] @ 98304 (11.0 MB)
#define COUNTS_WORDS (BATCH * NCHUNK * BINB)
#define ENTRIES_OFF  (COUNTS_WORDS * 4)
#define WS_NEEDED    (ENTRIES_OFF + (size_t)BATCH * NCHUNK * BINB * CAP_B * 2)

typedef float f32x4 __attribute__((ext_vector_type(4)));
typedef int   i32x2 __attribute__((ext_vector_type(2)));
typedef unsigned int u32;
typedef unsigned short u16;

// Kernel A (unchanged — proven ~5 µs): single-scan bin, 16 blocks/sample,
// int2 NT index loads, LDS atomicAdd compaction, wave-parallel dump to
// dedicated slices. No global atomics, no memset.
__global__ __launch_bounds__(512) void bin_kernel(
    const int* __restrict__ indices, const int* __restrict__ num_salt,
    u32* __restrict__ counts, u16* __restrict__ entries)
{
    __shared__ u16 stage[NCHUNK][CAP_B];
    __shared__ u32 lcnt[NCHUNK];
    const int b  = blockIdx.y;
    const int cb = blockIdx.x;
    const int t  = threadIdx.x;
    const int ns = num_salt[b];

    if (t < NCHUNK) lcnt[t] = 0;
    __syncthreads();

    const i32x2* __restrict__ ind2 = (const i32x2*)(indices + b * NSP);
    const int M = NSP / 2;                   // 27525 int2s (exact)
    for (int m = cb * 512 + t; m < M; m += BINB * 512) {
        i32x2 p2 = __builtin_nontemporal_load(ind2 + m);
        #pragma unroll
        for (int h = 0; h < 2; ++h) {
            int p = p2[h];
            int j = 2 * m + h;
            int q = p >> LOG_CHUNK;
            u32 r = atomicAdd(&lcnt[q], 1u);
            u16 e = (u16)((p & (CHUNK_PX - 1)) | ((j < ns) ? 0x8000u : 0u));
            if (r < CAP_B) stage[q][r] = e;
        }
    }
    __syncthreads();

    const int w = t >> 6, lane = t & 63;
    for (int q = w; q < NCHUNK; q += 8) {
        u32 c = lcnt[q]; if (c > CAP_B) c = CAP_B;
        if (lane == 0) counts[(b * NCHUNK + q) * BINB + cb] = c;
        u16* __restrict__ dst = entries + ((size_t)(b * NCHUNK + q) * BINB + cb) * CAP_B;
        for (u32 e = lane; e < c; e += 64) dst[e] = stage[q][e];
    }
}

// A/B this round: NT store on the stream (output never re-read on device;
// bypass L2 write-allocate). Everything else frozen vs round 11.
#define DECODE_STORE(v, i)                                                     \
    {                                                                          \
        u32 m = (smask[(i) >> 2] >> (((i) & 3) * 8)) & 0xFFu;                  \
        f32x4 o;                                                               \
        o.x = (m & 1u)  ? (float)((m >> 1) & 1u) : fminf(fmaxf(v.x, 0.f), 1.f);\
        o.y = (m & 4u)  ? (float)((m >> 3) & 1u) : fminf(fmaxf(v.y, 0.f), 1.f);\
        o.z = (m & 16u) ? (float)((m >> 5) & 1u) : fminf(fmaxf(v.z, 0.f), 1.f);\
        o.w = (m & 64u) ? (float)((m >> 7) & 1u) : fminf(fmaxf(v.w, 0.f), 1.f);\
        __builtin_nontemporal_store(o, op + (i));                              \
    }

// Kernel B: per 32768-px chunk (512 threads).
//  - PF=8 issue-early stream loads before the mask build.
//  - Wave-parallel mask build (wave w owns slices {w, w+8}); disjoint-bit
//    LDS atomicOr -> order-independent -> deterministic.
__global__ __launch_bounds__(512) void apply_kernel(
    const f32x4* __restrict__ in, f32x4* __restrict__ out,
    const u32* __restrict__ counts, const u16* __restrict__ entries)
{
    __shared__ u32 smask[MASK_WORDS];
    const int b = blockIdx.y, q = blockIdx.x, t = threadIdx.x;

    const size_t base4 = (size_t)(b * NCHUNK + q) * F4_PER_CHUNK;
    const f32x4* __restrict__ ip = in + base4;
    f32x4* __restrict__ op = out + base4;

    // --- issue-early: first PF stream loads (independent of the mask) ---
    f32x4 pf[PF];
    #pragma unroll
    for (int k = 0; k < PF; ++k)
        pf[k] = __builtin_nontemporal_load(ip + k * 512 + t);

    // --- mask zero + wave-parallel build ---
    #pragma unroll
    for (int w = t; w < MASK_WORDS; w += 512) smask[w] = 0u;
    __syncthreads();

    const u32* __restrict__ cp = counts + (b * NCHUNK + q) * BINB;
    const u16* __restrict__ ep = entries + (size_t)(b * NCHUNK + q) * BINB * CAP_B;
    const int w = t >> 6, lane = t & 63;
    #pragma unroll
    for (int s = 0; s < 2; ++s) {
        const int cb = w + s * 8;
        u32 cnt = cp[cb];                      // same addr across wave -> broadcast
        const u16* __restrict__ sl = ep + cb * CAP_B;
        for (u32 e = lane; e < cnt; e += 64) {
            u32 v = sl[e];
            u32 lp = v & (CHUNK_PX - 1);
            u32 bits = (1u | ((v >> 15) << 1)) << ((lp & 15) * 2);
            atomicOr(&smask[lp >> 4], bits);
        }
    }
    __syncthreads();

    // --- drain prefetched iterations ---
    #pragma unroll
    for (int k = 0; k < PF; ++k)
        DECODE_STORE(pf[k], k * 512 + t)

    // --- remaining stream iterations ---
    #pragma unroll
    for (int kk = PF; kk < F4_PER_CHUNK / 512; ++kk) {
        int i = kk * 512 + t;
        f32x4 v = __builtin_nontemporal_load(ip + i);
        DECODE_STORE(v, i)
    }
}

// ---- fallback (ws too small): proven round-2/4 two-pass path ----
__global__ __launch_bounds__(256) void copy_clip_kernel(
    const f32x4* __restrict__ in, f32x4* __restrict__ out, int n4) {
    int stride = gridDim.x * blockDim.x;
    for (int i = blockIdx.x * blockDim.x + threadIdx.x; i < n4; i += stride) {
        f32x4 v = __builtin_nontemporal_load(in + i);
        v.x = fminf(fmaxf(v.x, 0.f), 1.f); v.y = fminf(fmaxf(v.y, 0.f), 1.f);
        v.z = fminf(fmaxf(v.z, 0.f), 1.f); v.w = fminf(fmaxf(v.w, 0.f), 1.f);
        out[i] = v;
    }
}
__global__ __launch_bounds__(256) void scatter_kernel(
    const int* __restrict__ indices, const int* __restrict__ num_salt,
    float* __restrict__ out) {
    int b = blockIdx.y;
    int j = blockIdx.x * blockDim.x + threadIdx.x;
    if (j >= NSP) return;
    out[(size_t)b * NPIX + indices[b * NSP + j]] = (j < num_salt[b]) ? 1.0f : 0.0f;
}

extern "C" void kernel_launch(void* const* d_in, const int* in_sizes, int n_in,
                              void* d_out, int out_size, void* d_ws, size_t ws_size,
                              hipStream_t stream) {
    const float* x        = (const float*)d_in[0];
    const int*   indices  = (const int*)d_in[1];
    const int*   num_salt = (const int*)d_in[2];
    float*       out      = (float*)d_out;

    if (ws_size >= WS_NEEDED) {
        u32* counts  = (u32*)d_ws;
        u16* entries = (u16*)((char*)d_ws + ENTRIES_OFF);
        dim3 agrid(BINB, BATCH);               // (16, 64) x 512 thr
        bin_kernel<<<agrid, 512, 0, stream>>>(indices, num_salt, counts, entries);
        dim3 bgrid(NCHUNK, BATCH);             // (24, 64) x 512 thr
        apply_kernel<<<bgrid, 512, 0, stream>>>(
            (const f32x4*)x, (f32x4*)out, counts, entries);
    } else {
        int n4 = out_size / 4;
        copy_clip_kernel<<<2048, 256, 0, stream>>>((const f32x4*)x, (f32x4*)out, n4);
        dim3 sgrid((NSP + 255) / 256, BATCH);
        scatter_kernel<<<sgrid, 256, 0, stream>>>(indices, num_salt, out);
    }
}

// Round 13
// 78.674 us; speedup vs baseline: 1.1146x; 1.1146x over previous
//
#include <hip/hip_runtime.h>

// Problem constants (from reference)
#define NPIX     786432                     // C*H*W = 3*512*512
#define NSP      55050                      // noise pixels per sample
#define BATCH    64
#define LOG_CHUNK 15
#define CHUNK_PX (1 << LOG_CHUNK)           // 32768 pixels per chunk
#define NCHUNK   (NPIX / CHUNK_PX)          // 24 chunks per sample
#define BINB     16                         // bin blocks per sample
#define CAP_B    224                        // entries per (sample,chunk,binblock)
#define F4_PER_CHUNK (CHUNK_PX / 4)         // 8192 float4
#define MASK_WORDS   (CHUNK_PX / 16)        // 2048 u32 = 8 KB LDS (2 bits/px)
#define PF       8                          // prefetched stream iterations

// ws layout: u32 counts[64][24][16] @ 0 (fully rewritten every call);
//            u16 entries[64][24][16][CAP_B] @ 98304 (11.0 MB)
#define COUNTS_WORDS (BATCH * NCHUNK * BINB)
#define ENTRIES_OFF  (COUNTS_WORDS * 4)
#define WS_NEEDED    (ENTRIES_OFF + (size_t)BATCH * NCHUNK * BINB * CAP_B * 2)

typedef float f32x4 __attribute__((ext_vector_type(4)));
typedef int   i32x2 __attribute__((ext_vector_type(2)));
typedef unsigned int u32;
typedef unsigned short u16;

// Kernel A (proven ~5 µs): single-scan bin, 16 blocks/sample, int2 NT index
// loads, LDS atomicAdd compaction, wave-parallel dump to dedicated slices.
// No global atomics, no memset.
__global__ __launch_bounds__(512) void bin_kernel(
    const int* __restrict__ indices, const int* __restrict__ num_salt,
    u32* __restrict__ counts, u16* __restrict__ entries)
{
    __shared__ u16 stage[NCHUNK][CAP_B];
    __shared__ u32 lcnt[NCHUNK];
    const int b  = blockIdx.y;
    const int cb = blockIdx.x;
    const int t  = threadIdx.x;
    const int ns = num_salt[b];

    if (t < NCHUNK) lcnt[t] = 0;
    __syncthreads();

    const i32x2* __restrict__ ind2 = (const i32x2*)(indices + b * NSP);
    const int M = NSP / 2;                   // 27525 int2s (exact)
    for (int m = cb * 512 + t; m < M; m += BINB * 512) {
        i32x2 p2 = __builtin_nontemporal_load(ind2 + m);
        #pragma unroll
        for (int h = 0; h < 2; ++h) {
            int p = p2[h];
            int j = 2 * m + h;
            int q = p >> LOG_CHUNK;
            u32 r = atomicAdd(&lcnt[q], 1u);
            u16 e = (u16)((p & (CHUNK_PX - 1)) | ((j < ns) ? 0x8000u : 0u));
            if (r < CAP_B) stage[q][r] = e;
        }
    }
    __syncthreads();

    const int w = t >> 6, lane = t & 63;
    for (int q = w; q < NCHUNK; q += 8) {
        u32 c = lcnt[q]; if (c > CAP_B) c = CAP_B;
        if (lane == 0) counts[(b * NCHUNK + q) * BINB + cb] = c;
        u16* __restrict__ dst = entries + ((size_t)(b * NCHUNK + q) * BINB + cb) * CAP_B;
        for (u32 e = lane; e < c; e += 64) dst[e] = stage[q][e];
    }
}

// Round-12 A/B verdict: PLAIN stores win (NT stores cost +9 µs on gfx950 —
// the L2 write-allocate path sustains higher write BW). NT only on loads.
#define DECODE_STORE(v, i)                                                     \
    {                                                                          \
        u32 m = (smask[(i) >> 2] >> (((i) & 3) * 8)) & 0xFFu;                  \
        f32x4 o;                                                               \
        o.x = (m & 1u)  ? (float)((m >> 1) & 1u) : fminf(fmaxf(v.x, 0.f), 1.f);\
        o.y = (m & 4u)  ? (float)((m >> 3) & 1u) : fminf(fmaxf(v.y, 0.f), 1.f);\
        o.z = (m & 16u) ? (float)((m >> 5) & 1u) : fminf(fmaxf(v.z, 0.f), 1.f);\
        o.w = (m & 64u) ? (float)((m >> 7) & 1u) : fminf(fmaxf(v.w, 0.f), 1.f);\
        op[i] = o;                                                             \
    }

// Kernel B (round-11 proven 78.4 µs config): per 32768-px chunk, 512 threads.
//  - PF=8 issue-early stream loads before the mask build.
//  - Wave-parallel mask build (wave w owns slices {w, w+8}); disjoint-bit
//    LDS atomicOr -> order-independent -> deterministic.
__global__ __launch_bounds__(512) void apply_kernel(
    const f32x4* __restrict__ in, f32x4* __restrict__ out,
    const u32* __restrict__ counts, const u16* __restrict__ entries)
{
    __shared__ u32 smask[MASK_WORDS];
    const int b = blockIdx.y, q = blockIdx.x, t = threadIdx.x;

    const size_t base4 = (size_t)(b * NCHUNK + q) * F4_PER_CHUNK;
    const f32x4* __restrict__ ip = in + base4;
    f32x4* __restrict__ op = out + base4;

    // --- issue-early: first PF stream loads (independent of the mask) ---
    f32x4 pf[PF];
    #pragma unroll
    for (int k = 0; k < PF; ++k)
        pf[k] = __builtin_nontemporal_load(ip + k * 512 + t);

    // --- mask zero + wave-parallel build ---
    #pragma unroll
    for (int w = t; w < MASK_WORDS; w += 512) smask[w] = 0u;
    __syncthreads();

    const u32* __restrict__ cp = counts + (b * NCHUNK + q) * BINB;
    const u16* __restrict__ ep = entries + (size_t)(b * NCHUNK + q) * BINB * CAP_B;
    const int w = t >> 6, lane = t & 63;
    #pragma unroll
    for (int s = 0; s < 2; ++s) {
        const int cb = w + s * 8;
        u32 cnt = cp[cb];                      // same addr across wave -> broadcast
        const u16* __restrict__ sl = ep + cb * CAP_B;
        for (u32 e = lane; e < cnt; e += 64) {
            u32 v = sl[e];
            u32 lp = v & (CHUNK_PX - 1);
            u32 bits = (1u | ((v >> 15) << 1)) << ((lp & 15) * 2);
            atomicOr(&smask[lp >> 4], bits);
        }
    }
    __syncthreads();

    // --- drain prefetched iterations ---
    #pragma unroll
    for (int k = 0; k < PF; ++k)
        DECODE_STORE(pf[k], k * 512 + t)

    // --- remaining stream iterations ---
    #pragma unroll
    for (int kk = PF; kk < F4_PER_CHUNK / 512; ++kk) {
        int i = kk * 512 + t;
        f32x4 v = __builtin_nontemporal_load(ip + i);
        DECODE_STORE(v, i)
    }
}

// ---- fallback (ws too small): proven round-2/4 two-pass path ----
__global__ __launch_bounds__(256) void copy_clip_kernel(
    const f32x4* __restrict__ in, f32x4* __restrict__ out, int n4) {
    int stride = gridDim.x * blockDim.x;
    for (int i = blockIdx.x * blockDim.x + threadIdx.x; i < n4; i += stride) {
        f32x4 v = __builtin_nontemporal_load(in + i);
        v.x = fminf(fmaxf(v.x, 0.f), 1.f); v.y = fminf(fmaxf(v.y, 0.f), 1.f);
        v.z = fminf(fmaxf(v.z, 0.f), 1.f); v.w = fminf(fmaxf(v.w, 0.f), 1.f);
        out[i] = v;
    }
}
__global__ __launch_bounds__(256) void scatter_kernel(
    const int* __restrict__ indices, const int* __restrict__ num_salt,
    float* __restrict__ out) {
    int b = blockIdx.y;
    int j = blockIdx.x * blockDim.x + threadIdx.x;
    if (j >= NSP) return;
    out[(size_t)b * NPIX + indices[b * NSP + j]] = (j < num_salt[b]) ? 1.0f : 0.0f;
}

extern "C" void kernel_launch(void* const* d_in, const int* in_sizes, int n_in,
                              void* d_out, int out_size, void* d_ws, size_t ws_size,
                              hipStream_t stream) {
    const float* x        = (const float*)d_in[0];
    const int*   indices  = (const int*)d_in[1];
    const int*   num_salt = (const int*)d_in[2];
    float*       out      = (float*)d_out;

    if (ws_size >= WS_NEEDED) {
        u32* counts  = (u32*)d_ws;
        u16* entries = (u16*)((char*)d_ws + ENTRIES_OFF);
        dim3 agrid(BINB, BATCH);               // (16, 64) x 512 thr
        bin_kernel<<<agrid, 512, 0, stream>>>(indices, num_salt, counts, entries);
        dim3 bgrid(NCHUNK, BATCH);             // (24, 64) x 512 thr
        apply_kernel<<<bgrid, 512, 0, stream>>>(
            (const f32x4*)x, (f32x4*)out, counts, entries);
    } else {
        int n4 = out_size / 4;
        copy_clip_kernel<<<2048, 256, 0, stream>>>((const f32x4*)x, (f32x4*)out, n4);
        dim3 sgrid((NSP + 255) / 256, BATCH);
        scatter_kernel<<<sgrid, 256, 0, stream>>>(indices, num_salt, out);
    }
}